// Round 1
// baseline (1720.463 us; speedup 1.0000x reference)
//
#include <hip/hip_runtime.h>
#include <math.h>

// RNN: h_t = tanh(x[b,t]*W_ih + b_ih + b_hh + h_{t-1} @ W_hh^T), out = h_T @ W_out^T + b_out
// B=256 T=2048 H=256 P=24, all fp32.
//
// Design: one workgroup per batch (256 WGs = 256 CUs). 512 threads/WG:
// thread (o = tid&255, half = tid>>8) computes output element o over K-half
// [half*128, half*128+128). W_hh half-row lives in 128 VGPRs (256KB doesn't fit
// LDS; L2 re-read would cost ~4700 cyc/step). h broadcast from LDS via float4.
// Two barriers/step: partial exchange, then h update.

#define BB 256
#define TT 2048
#define HH 256
#define PP 24

__global__ __launch_bounds__(512, 1)
void rnn_persist(const float* __restrict__ x,
                 const float* __restrict__ W_ih,
                 const float* __restrict__ W_hh,
                 const float* __restrict__ b_ih,
                 const float* __restrict__ b_hh,
                 const float* __restrict__ W_out,
                 const float* __restrict__ b_out,
                 float* __restrict__ out)
{
    __shared__ float lds_x[TT];
    __shared__ __align__(16) float lds_h[HH];
    __shared__ __align__(16) float lds_p[HH];

    const int tid  = threadIdx.x;
    const int b    = blockIdx.x;
    const int o    = tid & (HH - 1);
    const int half = tid >> 8;        // 0 or 1: which K-half this thread owns

    // Preload this batch's entire x sequence to LDS (8 KB), coalesced.
    for (int i = tid; i < TT; i += 512) lds_x[i] = x[b * TT + i];
    if (tid < HH) lds_h[tid] = 0.0f;  // h0 = 0

    // W_hh half-row -> registers (128 VGPRs). One-time, L2/L3-served.
    float w[128];
    const float* wrow = W_hh + o * HH + half * 128;
    #pragma unroll
    for (int j = 0; j < 128; ++j) w[j] = wrow[j];

    const float wih = W_ih[o];
    const float cb  = b_ih[o] + b_hh[o];

    __syncthreads();

    for (int t = 0; t < TT; ++t) {
        // 128 FMAs against broadcast h, 4 independent accumulator chains.
        float a0 = 0.f, a1 = 0.f, a2 = 0.f, a3 = 0.f;
        const float4* hv = (const float4*)(lds_h + half * 128);
        #pragma unroll
        for (int j = 0; j < 32; ++j) {
            float4 h4 = hv[j];
            a0 = fmaf(w[4*j+0], h4.x, a0);
            a1 = fmaf(w[4*j+1], h4.y, a1);
            a2 = fmaf(w[4*j+2], h4.z, a2);
            a3 = fmaf(w[4*j+3], h4.w, a3);
        }
        float acc = (a0 + a1) + (a2 + a3);

        if (half) lds_p[o] = acc;       // upper half publishes its partial
        __syncthreads();                 // also fences this step's lds_h reads
        if (!half) {
            float pre = fmaf(lds_x[t], wih, cb) + acc + lds_p[o];
            lds_h[o] = tanhf(pre);
        }
        __syncthreads();                 // h_t visible to everyone
    }

    // Head: out[b,p] = b_out[p] + sum_h W_out[p,h] * h_T[h]. Tiny (24x256), once.
    if (tid < PP) {
        const float* wo = W_out + tid * HH;
        float s0 = 0.f, s1 = 0.f, s2 = 0.f, s3 = 0.f;
        #pragma unroll
        for (int h = 0; h < HH; h += 4) {
            s0 = fmaf(wo[h+0], lds_h[h+0], s0);
            s1 = fmaf(wo[h+1], lds_h[h+1], s1);
            s2 = fmaf(wo[h+2], lds_h[h+2], s2);
            s3 = fmaf(wo[h+3], lds_h[h+3], s3);
        }
        out[b * PP + tid] = b_out[tid] + (s0 + s1) + (s2 + s3);
    }
}

extern "C" void kernel_launch(void* const* d_in, const int* in_sizes, int n_in,
                              void* d_out, int out_size, void* d_ws, size_t ws_size,
                              hipStream_t stream) {
    const float* x     = (const float*)d_in[0];
    const float* W_ih  = (const float*)d_in[1];
    const float* W_hh  = (const float*)d_in[2];
    const float* b_ih  = (const float*)d_in[3];
    const float* b_hh  = (const float*)d_in[4];
    const float* W_out = (const float*)d_in[5];
    const float* b_out = (const float*)d_in[6];
    float* out = (float*)d_out;

    rnn_persist<<<BB, 512, 0, stream>>>(x, W_ih, W_hh, b_ih, b_hh, W_out, b_out, out);
}